// Round 18
// baseline (39.378 us; speedup 1.0000x reference)
//
#include <hip/hip_runtime.h>

// Cost volume: corr[b, dyi*9+dxi, y, x] = sum_c f1[b,c,y,x] * f2[b,c,y+dyi-4,x+dxi-4]
// (OOB f2 = 0). B=4, C=256, H=W=96, patch 9x9.
//
// Round 18 = round 15/17 core + y-PAIR blocks (L2-traffic cut).
//  R16/R17 latency restructures were neutral -> main is L2-BW-bound
//  (~33 B/cy/CU = the L2 ceiling). Fix: reuse each B-fragment for TWO y's.
//  - Block = (b, ypair, mt), 320 thr = 5 waves; wave w owns y2 rows
//    {y0-4+2w, y0-4+2w+1} (10 rows total, was 2x9). Per (y2,tile): load B[8]
//    once, MFMA into acc0 (y=y0, dy=2w+rr if <=8) and acc1 (y=y1, dy-1 if
//    >=1). Coverage exact & disjoint. B-traffic 331 -> 184 MB.
//  - A-frags for both y's staged in LDS (as R15), a[2][8] = 64 VGPR.
//  - Grid 1152 = 8*144 bijective XCD swizzle; LDS 30.4 KB; no launch-bounds
//    min-waves (VGPR ~140 needed).
//  Pack (f2-only channel-major f16) and fallback unchanged.

typedef _Float16 f16x8 __attribute__((ext_vector_type(8)));
typedef float f32x4 __attribute__((ext_vector_type(4)));

#define NB 4
#define NC 256
#define NH 96
#define NW 96
#define NP 9
#define PLANE (NH * NW)                       // 9216
#define TENS (NB * NH * NW * NC)              // 9,437,184 f16 (f2 only)
#define WS_NEED ((unsigned long long)TENS * 2ull)  // 18,874,368 B
#define TPT4 (TENS / 32)                      // 294,912 pack threads
#define PACK_BLK (TPT4 / 256)                 // 1152
#define MAIN_BLK 1152                         // 4b * 48yp * 6mt
#define CGSTR (NW * 8)                        // 768 f16 per cg-plane
#define ROWSTR (32 * CGSTR)                   // 24576 f16 per (b,y) row
#define AROW 272                              // A-tile row stride in f16 (544 B)
#define LPAD 37                               // fallback kernel pad

// ---------- prepass: f2 f32 [b][c][y][x] -> f16 [b][y][cg][x][8] ------------
__global__ __launch_bounds__(256) void pack_f2(const float* __restrict__ f2,
                                               _Float16* __restrict__ ws)
{
    const int e   = blockIdx.x * 256 + threadIdx.x;   // 0 .. 294,911
    const int row = e / 768;                          // b*96 + y   (384)
    const int q   = e % 768;
    const int cg  = q / 24;                           // 0..31
    const int x4  = q % 24;                           // lane-fastest (coalesced)
    const int b   = row / NH;
    const int y   = row % NH;

    const float* sp = f2 + ((size_t)(b * NC + cg * 8) * NH + y) * NW + x4 * 4;
    float vv[8][4];
#pragma unroll
    for (int j = 0; j < 8; ++j) {
        const float4 v = *(const float4*)(sp + (size_t)j * PLANE);
        vv[j][0] = v.x; vv[j][1] = v.y; vv[j][2] = v.z; vv[j][3] = v.w;
    }
    _Float16* dp = ws + ((size_t)row * 32 + cg) * CGSTR + (size_t)x4 * 32;
#pragma unroll
    for (int xi = 0; xi < 4; ++xi) {
        f16x8 o;
#pragma unroll
        for (int j = 0; j < 8; ++j) o[j] = (_Float16)vv[j][xi];
        *(f16x8*)(dp + xi * 8) = o;
    }
}

// ---------- main: MFMA banded Gram, y-pair blocks ---------------------------
__global__ __launch_bounds__(320) void costvol_mfma(const float* __restrict__ f1,
                                                    const _Float16* __restrict__ f2p,
                                                    float* __restrict__ out)
{
    __shared__ _Float16 lds_a[2][16 * AROW];      // 17,408 B
    __shared__ float ldso[2][81][20];             // 12,960 B

    const int bid = blockIdx.x;
    const int swz = (bid & 7) * (MAIN_BLK / 8) + (bid >> 3);
    const int mt  = swz % 6;
    const int yp  = (swz / 6) % 48;
    const int b   = swz / 288;
    const int y0  = yp * 2;                       // y-pair: y0, y0+1

    const int w    = threadIdx.x >> 6;            // wave 0..4
    const int lane = threadIdx.x & 63;
    const int lr   = lane & 15;
    const int lg   = lane >> 4;
    const int m0   = mt * 16;

    // --- cooperative A staging: 2048 float4 tasks (2 y-rows) over 320 thr --
#pragma unroll
    for (int i = 0; i < 7; ++i) {
        const int t = threadIdx.x + i * 320;      // 0..2239
        if (t < 2048) {
            const int yloc = t >> 10;
            const int r    = t & 1023;
            const int c    = r >> 2;
            const int xq   = r & 3;
            const float4 v = *(const float4*)(
                f1 + ((size_t)(b * NC + c) * NH + (y0 + yloc)) * NW + m0 + xq * 4);
            _Float16* d0 = lds_a[yloc] + (size_t)(xq * 4) * AROW + c;
            d0[0 * AROW] = (_Float16)v.x;
            d0[1 * AROW] = (_Float16)v.y;
            d0[2 * AROW] = (_Float16)v.z;
            d0[3 * AROW] = (_Float16)v.w;
        }
    }
    __syncthreads();

    // A-frag read for both y's: lane (lr,lg); c = ks*32 + lg*8 + j
    f16x8 a[2][8];
#pragma unroll
    for (int yloc = 0; yloc < 2; ++yloc) {
        const _Float16* ap = lds_a[yloc] + (size_t)lr * AROW + lg * 8;
#pragma unroll
        for (int ks = 0; ks < 8; ++ks) a[yloc][ks] = *(const f16x8*)(ap + ks * 32);
    }

    const f16x8 bz = {};
    const int y2a = y0 - 4 + 2 * w;               // this wave's first y2 row

#pragma unroll
    for (int rr = 0; rr < 2; ++rr) {
        const int y2  = y2a + rr;
        const int dys = 2 * w + rr;               // dy for y0; y1 uses dys-1
        const bool val0 = (dys <= 8);             // wave-uniform
        const bool val1 = (dys >= 1);
        const bool inb  = (y2 >= 0) && (y2 < 96);
        const _Float16* rbase = f2p + (size_t)(b * 96 + (inb ? y2 : 0)) * ROWSTR
                              + (size_t)lg * CGSTR;
#pragma unroll
        for (int tl = 0; tl < 2; ++tl) {
            const int n0   = m0 + (tl ? 8 : -8) + lr;   // x' column (per-lane)
            const bool inN = tl ? (n0 < 96) : (n0 >= 0);
            f32x4 acc0 = {0.f, 0.f, 0.f, 0.f};
            f32x4 acc1 = {0.f, 0.f, 0.f, 0.f};

            if (inb) {
                const _Float16* pb = rbase + (ptrdiff_t)n0 * 8;
                f16x8 B[8];
#pragma unroll
                for (int ks = 0; ks < 8; ++ks)
                    B[ks] = inN ? *(const f16x8*)(pb + (size_t)ks * 4 * CGSTR) : bz;
                if (val0) {
#pragma unroll
                    for (int ks = 0; ks < 8; ++ks)
                        acc0 = __builtin_amdgcn_mfma_f32_16x16x32_f16(a[0][ks], B[ks], acc0, 0, 0, 0);
                }
                if (val1) {
#pragma unroll
                    for (int ks = 0; ks < 8; ++ks)
                        acc1 = __builtin_amdgcn_mfma_f32_16x16x32_f16(a[1][ks], B[ks], acc1, 0, 0, 0);
                }
            }

            // stage: D row m = m0+lg*4+reg, col n = lr; dx = lr-mrow+(tl?12:-4)
#pragma unroll
            for (int reg = 0; reg < 4; ++reg) {
                const int mrow = lg * 4 + reg;
                const int dx   = lr - mrow + (tl ? 12 : -4);
                if (dx >= 0 && dx <= 8) {
                    if (val0) ldso[0][dys * 9 + dx][mrow] = acc0[reg];
                    if (val1) ldso[1][(dys - 1) * 9 + dx][mrow] = acc1[reg];
                }
            }
        }
    }

    __syncthreads();

    // coalesced writeout: 162 rows (2 y x 81), each a 64B line
    const int q = (threadIdx.x & 3) * 4;
#pragma unroll
    for (int ri = threadIdx.x >> 2; ri < 162; ri += 80) {
        const int yloc = ri / 81;
        const int r    = ri - yloc * 81;
        const float4 v = make_float4(ldso[yloc][r][q], ldso[yloc][r][q + 1],
                                     ldso[yloc][r][q + 2], ldso[yloc][r][q + 3]);
        *(float4*)(out + ((size_t)(b * 81 + r) * PLANE) + (y0 + yloc) * 96 + m0 + q) = v;
    }
}

// ---------- fallback: round-2 f32 kernel (if ws too small) ------------------
__global__ __launch_bounds__(256) void costvol_f32(const float* __restrict__ f1,
                                                   const float* __restrict__ f2,
                                                   float* __restrict__ out)
{
    __shared__ float lds[2 * 64 * LPAD];
    const int bid = blockIdx.x;
    const int swz = (bid & 7) * (1296 / 8) + (bid >> 3);
    const int dyi = swz % NP;
    const int g   = swz / NP;
    const int w    = threadIdx.x >> 6;
    const int lane = threadIdx.x & 63;
    const int chk = g * 64 + lane;
    const int b   = chk / (NH * 24);
    const int rem = chk - b * (NH * 24);
    const int y   = rem / 24;
    const int x0  = (rem - y * 24) * 4;
    const int y2  = y + dyi - 4;

    float acc[NP][4];
#pragma unroll
    for (int i = 0; i < NP; ++i)
#pragma unroll
        for (int j = 0; j < 4; ++j) acc[i][j] = 0.f;

    if (y2 >= 0 && y2 < NH) {
        const float* p1 = f1 + ((size_t)(b * NC + w * 64) * NH + y) * NW + x0;
        const float* p2 = f2 + ((size_t)(b * NC + w * 64) * NH + y2) * NW + x0;
        const bool hasL = (x0 >= 4);
        const bool hasR = (x0 <= NW - 8);
#pragma unroll 4
        for (int c = 0; c < 64; ++c) {
            const float4 av = *(const float4*)p1;
            const float4 Lv = hasL ? *(const float4*)(p2 - 4) : make_float4(0.f, 0.f, 0.f, 0.f);
            const float4 Mv = *(const float4*)(p2);
            const float4 Rv = hasR ? *(const float4*)(p2 + 4) : make_float4(0.f, 0.f, 0.f, 0.f);
            const float wv[12] = {Lv.x, Lv.y, Lv.z, Lv.w, Mv.x, Mv.y, Mv.z, Mv.w,
                                  Rv.x, Rv.y, Rv.z, Rv.w};
            const float aa[4] = {av.x, av.y, av.z, av.w};
#pragma unroll
            for (int dxi = 0; dxi < NP; ++dxi)
#pragma unroll
                for (int j = 0; j < 4; ++j) acc[dxi][j] += aa[j] * wv[dxi + j];
            p1 += PLANE;
            p2 += PLANE;
        }
    }

    float* reg0 = &lds[0 * 64 * LPAD + lane * LPAD];
    float* reg1 = &lds[1 * 64 * LPAD + lane * LPAD];
    if (w >= 2) {
        float* dst = (w == 2) ? reg0 : reg1;
#pragma unroll
        for (int dxi = 0; dxi < NP; ++dxi)
#pragma unroll
            for (int j = 0; j < 4; ++j) dst[dxi * 4 + j] = acc[dxi][j];
    }
    __syncthreads();
    if (w < 2) {
        const float* src = (w == 0) ? reg0 : reg1;
#pragma unroll
        for (int dxi = 0; dxi < NP; ++dxi)
#pragma unroll
            for (int j = 0; j < 4; ++j) acc[dxi][j] += src[dxi * 4 + j];
    }
    __syncthreads();
    if (w == 1) {
#pragma unroll
        for (int dxi = 0; dxi < NP; ++dxi)
#pragma unroll
            for (int j = 0; j < 4; ++j) reg0[dxi * 4 + j] = acc[dxi][j];
    }
    __syncthreads();
    if (w == 0) {
#pragma unroll
        for (int dxi = 0; dxi < NP; ++dxi)
#pragma unroll
            for (int j = 0; j < 4; ++j) acc[dxi][j] += reg0[dxi * 4 + j];
        float* ob = out + ((size_t)(b * 81 + dyi * 9) * NH + y) * NW + x0;
#pragma unroll
        for (int dxi = 0; dxi < NP; ++dxi) {
            *(float4*)ob = make_float4(acc[dxi][0], acc[dxi][1], acc[dxi][2], acc[dxi][3]);
            ob += PLANE;
        }
    }
}

extern "C" void kernel_launch(void* const* d_in, const int* in_sizes, int n_in,
                              void* d_out, int out_size, void* d_ws, size_t ws_size,
                              hipStream_t stream) {
    const float* f1 = (const float*)d_in[0];
    const float* f2 = (const float*)d_in[1];
    float* out = (float*)d_out;
    if (ws_size >= WS_NEED) {
        _Float16* ws = (_Float16*)d_ws;
        pack_f2<<<dim3(PACK_BLK, 1, 1), dim3(256, 1, 1), 0, stream>>>(f2, ws);
        costvol_mfma<<<dim3(MAIN_BLK, 1, 1), dim3(320, 1, 1), 0, stream>>>(f1, ws, out);
    } else {
        costvol_f32<<<dim3(1296, 1, 1), dim3(256, 1, 1), 0, stream>>>(f1, f2, out);
    }
}

// Round 19
// 37.483 us; speedup vs baseline: 1.0506x; 1.0506x over previous
//
#include <hip/hip_runtime.h>

// Cost volume: corr[b, dyi*9+dxi, y, x] = sum_c f1[b,c,y,x] * f2[b,c,y+dyi-4,x+dxi-4]
// (OOB f2 = 0). B=4, C=256, H=W=96, patch 9x9.
//
// Round 19 = round 15 (best: 38.5us) with CONFLICT-FREE A-staging:
//  R15's A-stage used 4x ds_write_b16 per task into [x][c] rows of 544B
//  (17 banks*32B): all 4 xq-rows of one instr hit the SAME bank + 2 lanes
//  per word -> ~8-16-way serialized LDS writes before the barrier (R14
//  measured 414K conflicts). Fix:
//   - task = (c4, xq): 4 float4 loads (channels c4*4..+3, one x-quad),
//     repack to 4 f16x4, 4x ds_write_b64 (4 contiguous f16 along c).
//   - AROW 272 -> 276 (552B row = 138 words; 138 mod 32 = 10): rows spread
//     over all banks; <=2-way aliasing = free (m136).
//   - frag read b128 -> 2x b64 (552B rows are 8B-aligned).
//  Everything else (B-path, LDS out-staging, writeout, pack, swizzles)
//  unchanged from R15.

typedef _Float16 f16x4 __attribute__((ext_vector_type(4)));
typedef _Float16 f16x8 __attribute__((ext_vector_type(8)));
typedef float f32x4 __attribute__((ext_vector_type(4)));

#define NB 4
#define NC 256
#define NH 96
#define NW 96
#define NP 9
#define PLANE (NH * NW)                       // 9216
#define TENS (NB * NH * NW * NC)              // 9,437,184 f16 (f2 only)
#define WS_NEED ((unsigned long long)TENS * 2ull)  // 18,874,368 B
#define TPT4 (TENS / 32)                      // 294,912 pack threads
#define PACK_BLK (TPT4 / 256)                 // 1152
#define MAIN_BLK 2304                         // 4b * 96y * 6mt
#define CGSTR (NW * 8)                        // 768 f16 per cg-plane
#define ROWSTR (32 * CGSTR)                   // 24576 f16 per (b,y) row
#define AROW 276                              // A row stride f16 (552B, 138w, %32=10)
#define LPAD 37                               // fallback kernel pad

// ---------- prepass: f2 f32 [b][c][y][x] -> f16 [b][y][cg][x][8] ------------
__global__ __launch_bounds__(256) void pack_f2(const float* __restrict__ f2,
                                               _Float16* __restrict__ ws)
{
    const int e   = blockIdx.x * 256 + threadIdx.x;   // 0 .. 294,911
    const int row = e / 768;                          // b*96 + y   (384)
    const int q   = e % 768;
    const int cg  = q / 24;                           // 0..31
    const int x4  = q % 24;                           // lane-fastest (coalesced)
    const int b   = row / NH;
    const int y   = row % NH;

    const float* sp = f2 + ((size_t)(b * NC + cg * 8) * NH + y) * NW + x4 * 4;
    float vv[8][4];
#pragma unroll
    for (int j = 0; j < 8; ++j) {
        const float4 v = *(const float4*)(sp + (size_t)j * PLANE);
        vv[j][0] = v.x; vv[j][1] = v.y; vv[j][2] = v.z; vv[j][3] = v.w;
    }
    _Float16* dp = ws + ((size_t)row * 32 + cg) * CGSTR + (size_t)x4 * 32;
#pragma unroll
    for (int xi = 0; xi < 4; ++xi) {
        f16x8 o;
#pragma unroll
        for (int j = 0; j < 8; ++j) o[j] = (_Float16)vv[j][xi];
        *(f16x8*)(dp + xi * 8) = o;
    }
}

// ---------- main: MFMA banded Gram, conflict-free LDS-staged A --------------
__global__ __launch_bounds__(192) void costvol_mfma(const float* __restrict__ f1,
                                                    const _Float16* __restrict__ f2p,
                                                    float* __restrict__ out)
{
    __shared__ _Float16 lds_a[16 * AROW];         // 8832 B
    __shared__ float ldso[81][20];                // 6480 B

    const int bid = blockIdx.x;
    const int swz = (bid & 7) * (MAIN_BLK / 8) + (bid >> 3);
    const int mt  = swz % 6;
    const int y   = (swz / 6) % 96;
    const int b   = swz / 576;

    const int w    = threadIdx.x >> 6;            // wave 0..2 = dy-triplet
    const int lane = threadIdx.x & 63;
    const int lr   = lane & 15;
    const int lg   = lane >> 4;
    const int m0   = mt * 16;

    // --- cooperative A staging: 256 tasks (c4, xq); 4 float4 loads each;
    //     4x ds_write_b64 of 4 c-contiguous f16 -> conflict-free (<=2-way) --
#pragma unroll
    for (int i = 0; i < 2; ++i) {
        const int t = threadIdx.x + i * 192;      // 0..383
        if (t < 256) {
            const int xq = t & 3;
            const int c4 = t >> 2;                // 0..63
            float v[4][4];
#pragma unroll
            for (int j = 0; j < 4; ++j) {
                const float4 vj = *(const float4*)(
                    f1 + ((size_t)(b * NC + c4 * 4 + j) * NH + y) * NW + m0 + xq * 4);
                v[j][0] = vj.x; v[j][1] = vj.y; v[j][2] = vj.z; v[j][3] = vj.w;
            }
#pragma unroll
            for (int xi = 0; xi < 4; ++xi) {
                f16x4 h;
#pragma unroll
                for (int j = 0; j < 4; ++j) h[j] = (_Float16)v[j][xi];
                *(f16x4*)(lds_a + (size_t)(xq * 4 + xi) * AROW + c4 * 4) = h;
            }
        }
    }
    __syncthreads();

    // A-frag read: lane (lr,lg); ks: 8 f16 at row lr, col ks*32 + lg*8 (2x b64)
    f16x8 a[8];
    {
        const _Float16* ap = lds_a + (size_t)lr * AROW + lg * 8;
#pragma unroll
        for (int ks = 0; ks < 8; ++ks) {
            const f16x4 lo = *(const f16x4*)(ap + ks * 32);
            const f16x4 hi = *(const f16x4*)(ap + ks * 32 + 4);
            f16x8 o;
            o[0] = lo[0]; o[1] = lo[1]; o[2] = lo[2]; o[3] = lo[3];
            o[4] = hi[0]; o[5] = hi[1]; o[6] = hi[2]; o[7] = hi[3];
            a[ks] = o;
        }
    }

    const int n0a = m0 - 8 + lr;                  // x' tile 0 (may be <0)
    const int n0b = m0 + 8 + lr;                  // x' tile 1 (may be >=96)
    const bool inA = (n0a >= 0);
    const bool inB = (n0b < 96);
    const f16x8 bz = {};

#pragma unroll 1
    for (int i = 0; i < 3; ++i) {
        const int dy = w * 3 + i;
        const int y2 = y + dy - 4;
        f32x4 acc0 = {0.f, 0.f, 0.f, 0.f};
        f32x4 acc1 = {0.f, 0.f, 0.f, 0.f};

        if (y2 >= 0 && y2 < 96) {
            const _Float16* base = f2p + (size_t)(b * 96 + y2) * ROWSTR + (size_t)lg * CGSTR;
            const _Float16* pba  = base + (ptrdiff_t)n0a * 8;
            const _Float16* pbb  = base + (ptrdiff_t)n0b * 8;
            f16x8 B0[8], B1[8];
#pragma unroll
            for (int ks = 0; ks < 8; ++ks) {
                B0[ks] = inA ? *(const f16x8*)(pba + (size_t)ks * 4 * CGSTR) : bz;
                B1[ks] = inB ? *(const f16x8*)(pbb + (size_t)ks * 4 * CGSTR) : bz;
            }
#pragma unroll
            for (int ks = 0; ks < 8; ++ks) {
                acc0 = __builtin_amdgcn_mfma_f32_16x16x32_f16(a[ks], B0[ks], acc0, 0, 0, 0);
                acc1 = __builtin_amdgcn_mfma_f32_16x16x32_f16(a[ks], B1[ks], acc1, 0, 0, 0);
            }
        }

        // stage to LDS: D row m = m0+lg*4+reg, col n = lr; disjoint dx0/dx1
#pragma unroll
        for (int reg = 0; reg < 4; ++reg) {
            const int mrow = lg * 4 + reg;
            const int dx0  = lr - mrow - 4;       // tile0: x' = m0-8+lr
            const int dx1  = dx0 + 16;            // tile1: x' = m0+8+lr
            if (dx0 >= 0 && dx0 <= 8) ldso[dy * 9 + dx0][mrow] = acc0[reg];
            if (dx1 >= 0 && dx1 <= 8) ldso[dy * 9 + dx1][mrow] = acc1[reg];
        }
    }

    __syncthreads();

    // coalesced writeout: row r = dy*9+dx -> 64B line
    const int q = (threadIdx.x & 3) * 4;
#pragma unroll
    for (int r = threadIdx.x >> 2; r < 81; r += 48) {
        const float4 v = make_float4(ldso[r][q], ldso[r][q + 1],
                                     ldso[r][q + 2], ldso[r][q + 3]);
        *(float4*)(out + ((size_t)(b * 81 + r) * PLANE) + y * 96 + m0 + q) = v;
    }
}

// ---------- fallback: round-2 f32 kernel (if ws too small) ------------------
__global__ __launch_bounds__(256) void costvol_f32(const float* __restrict__ f1,
                                                   const float* __restrict__ f2,
                                                   float* __restrict__ out)
{
    __shared__ float lds[2 * 64 * LPAD];
    const int bid = blockIdx.x;
    const int swz = (bid & 7) * (1296 / 8) + (bid >> 3);
    const int dyi = swz % NP;
    const int g   = swz / NP;
    const int w    = threadIdx.x >> 6;
    const int lane = threadIdx.x & 63;
    const int chk = g * 64 + lane;
    const int b   = chk / (NH * 24);
    const int rem = chk - b * (NH * 24);
    const int y   = rem / 24;
    const int x0  = (rem - y * 24) * 4;
    const int y2  = y + dyi - 4;

    float acc[NP][4];
#pragma unroll
    for (int i = 0; i < NP; ++i)
#pragma unroll
        for (int j = 0; j < 4; ++j) acc[i][j] = 0.f;

    if (y2 >= 0 && y2 < NH) {
        const float* p1 = f1 + ((size_t)(b * NC + w * 64) * NH + y) * NW + x0;
        const float* p2 = f2 + ((size_t)(b * NC + w * 64) * NH + y2) * NW + x0;
        const bool hasL = (x0 >= 4);
        const bool hasR = (x0 <= NW - 8);
#pragma unroll 4
        for (int c = 0; c < 64; ++c) {
            const float4 av = *(const float4*)p1;
            const float4 Lv = hasL ? *(const float4*)(p2 - 4) : make_float4(0.f, 0.f, 0.f, 0.f);
            const float4 Mv = *(const float4*)(p2);
            const float4 Rv = hasR ? *(const float4*)(p2 + 4) : make_float4(0.f, 0.f, 0.f, 0.f);
            const float wv[12] = {Lv.x, Lv.y, Lv.z, Lv.w, Mv.x, Mv.y, Mv.z, Mv.w,
                                  Rv.x, Rv.y, Rv.z, Rv.w};
            const float aa[4] = {av.x, av.y, av.z, av.w};
#pragma unroll
            for (int dxi = 0; dxi < NP; ++dxi)
#pragma unroll
                for (int j = 0; j < 4; ++j) acc[dxi][j] += aa[j] * wv[dxi + j];
            p1 += PLANE;
            p2 += PLANE;
        }
    }

    float* reg0 = &lds[0 * 64 * LPAD + lane * LPAD];
    float* reg1 = &lds[1 * 64 * LPAD + lane * LPAD];
    if (w >= 2) {
        float* dst = (w == 2) ? reg0 : reg1;
#pragma unroll
        for (int dxi = 0; dxi < NP; ++dxi)
#pragma unroll
            for (int j = 0; j < 4; ++j) dst[dxi * 4 + j] = acc[dxi][j];
    }
    __syncthreads();
    if (w < 2) {
        const float* src = (w == 0) ? reg0 : reg1;
#pragma unroll
        for (int dxi = 0; dxi < NP; ++dxi)
#pragma unroll
            for (int j = 0; j < 4; ++j) acc[dxi][j] += src[dxi * 4 + j];
    }
    __syncthreads();
    if (w == 1) {
#pragma unroll
        for (int dxi = 0; dxi < NP; ++dxi)
#pragma unroll
            for (int j = 0; j < 4; ++j) reg0[dxi * 4 + j] = acc[dxi][j];
    }
    __syncthreads();
    if (w == 0) {
#pragma unroll
        for (int dxi = 0; dxi < NP; ++dxi)
#pragma unroll
            for (int j = 0; j < 4; ++j) acc[dxi][j] += reg0[dxi * 4 + j];
        float* ob = out + ((size_t)(b * 81 + dyi * 9) * NH + y) * NW + x0;
#pragma unroll
        for (int dxi = 0; dxi < NP; ++dxi) {
            *(float4*)ob = make_float4(acc[dxi][0], acc[dxi][1], acc[dxi][2], acc[dxi][3]);
            ob += PLANE;
        }
    }
}

extern "C" void kernel_launch(void* const* d_in, const int* in_sizes, int n_in,
                              void* d_out, int out_size, void* d_ws, size_t ws_size,
                              hipStream_t stream) {
    const float* f1 = (const float*)d_in[0];
    const float* f2 = (const float*)d_in[1];
    float* out = (float*)d_out;
    if (ws_size >= WS_NEED) {
        _Float16* ws = (_Float16*)d_ws;
        pack_f2<<<dim3(PACK_BLK, 1, 1), dim3(256, 1, 1), 0, stream>>>(f2, ws);
        costvol_mfma<<<dim3(MAIN_BLK, 1, 1), dim3(192, 1, 1), 0, stream>>>(f1, ws, out);
    } else {
        costvol_f32<<<dim3(1296, 1, 1), dim3(256, 1, 1), 0, stream>>>(f1, f2, out);
    }
}